// Round 1
// baseline (251.301 us; speedup 1.0000x reference)
//
#include <hip/hip_runtime.h>

typedef _Float16 half_t;
typedef _Float16 half8 __attribute__((ext_vector_type(8)));
typedef _Float16 half4 __attribute__((ext_vector_type(4)));
typedef _Float16 half2v __attribute__((ext_vector_type(2)));
typedef float f32x4 __attribute__((ext_vector_type(4)));

#define NELEM 16384
#define SROW 168   // LDS row stride in halves (dword stride 84 == 20 mod 32)

// ---------------------------------------------------------------------------
// In-wave fused network, OPERAND-SWAPPED: compute out^T = W^T * act^T.
//   A = weight frags (identical bytes to the old B-frags -> prep unchanged),
//   B = activation frags (identical addressing to the old A-loads).
// New D layout: D[outcol = q*4+r (+16*mt)][row = m (+16*nt)] -> each lane owns
// 4 CONTIGUOUS output columns of one row => vectorized half4/ds_write_b64
// epilogue, f32x4 bias (zero-padded table in ws), f32x4 gp add/store.
// Wave = 2 elements (40 rows -> 3 N-tiles of 16). Barrier-free, private LDS.
// Pad discipline: pad OUTPUT COLS always stored (= 0, since weights+bias are
// zero-padded) so K-pads stay zero; pad ROWS (40..47) never stored (junk is
// confined to pad N-columns of D by row-wise independence).
// ---------------------------------------------------------------------------

template<int KS, int NT>
__device__ __forceinline__ void load_bf(half8 (&bf)[KS][NT], const half_t* S, int m, int q) {
    #pragma unroll
    for (int ks = 0; ks < KS; ++ks)
        #pragma unroll
        for (int t = 0; t < NT; ++t)
            bf[ks][t] = *(const half8*)(S + (t*16 + m)*SROW + q*8 + ks*32);
}

// EPI: 0 = store activations at cols [0, MT*16), rows<40 when NT==3
//      1 = store f at col 112+, skipping cols >= 56 (mt==MT-1 && q>=2)
//      2 = logits: q==0 lanes -> lbufw[row] (+extra)
//      3 = gp: m<2 lanes -> gpb[m*112 + col] as f32x4
// INIT==1: add gpb[e*112 + col] (e = row>=20) before relu.
template<int KS, int NT, int MT, int EPI, int INIT, bool RELU>
__device__ __forceinline__ void run_layer(
    const half8 (&bf)[KS][NT], half_t* S,
    const half_t* __restrict__ wf, const float* __restrict__ biasp,
    float* gpb, float* lbufw, float extra, int lane)
{
    const int m = lane & 15, q = lane >> 4;
    #pragma unroll
    for (int mt = 0; mt < MT; ++mt) {
        half8 ah[KS];
        #pragma unroll
        for (int ks = 0; ks < KS; ++ks)
            ah[ks] = *(const half8*)(wf + ((size_t)(ks*MT + mt)*64 + lane)*8);
        f32x4 acc[NT];
        #pragma unroll
        for (int t = 0; t < NT; ++t) acc[t] = f32x4{0.f,0.f,0.f,0.f};
        __builtin_amdgcn_s_setprio(1);
        #pragma unroll
        for (int ks = 0; ks < KS; ++ks)
            #pragma unroll
            for (int t = 0; t < NT; ++t)
                acc[t] = __builtin_amdgcn_mfma_f32_16x16x32_f16(ah[ks], bf[ks][t], acc[t], 0, 0, 0);
        __builtin_amdgcn_s_setprio(0);
        const int col = mt*16 + q*4;
        f32x4 bv = {0.f,0.f,0.f,0.f};
        if constexpr (EPI == 0 || EPI == 1) bv = *(const f32x4*)(biasp + col);
        #pragma unroll
        for (int t = 0; t < NT; ++t) {
            const int row = t*16 + m;
            f32x4 v = acc[t] + bv;
            if constexpr (INIT == 1) {
                const int eoff = (t == 0) ? 0 : (t == 2) ? 112 : (m >= 4 ? 112 : 0);
                v += *(const f32x4*)(gpb + eoff + col);
            }
            if constexpr (RELU) {
                v[0] = fmaxf(v[0], 0.f); v[1] = fmaxf(v[1], 0.f);
                v[2] = fmaxf(v[2], 0.f); v[3] = fmaxf(v[3], 0.f);
            }
            if constexpr (EPI == 0) {
                bool ok = true;
                if constexpr (NT == 3) ok = (t < 2) || (m < 8);   // skip pad rows 40..47
                if (ok) {
                    half4 hv;
                    hv[0] = (half_t)v[0]; hv[1] = (half_t)v[1];
                    hv[2] = (half_t)v[2]; hv[3] = (half_t)v[3];
                    *(half4*)(S + row*SROW + col) = hv;
                }
            } else if constexpr (EPI == 1) {
                // f strip: cols 112..167; mt==MT-1 && q>=2 would overrun SROW
                if (((t < 2) || (m < 8)) && (mt < MT-1 || q < 2)) {
                    half4 hv;
                    hv[0] = (half_t)v[0]; hv[1] = (half_t)v[1];
                    hv[2] = (half_t)v[2]; hv[3] = (half_t)v[3];
                    *(half4*)(S + row*SROW + 112 + col) = hv;
                }
            } else if constexpr (EPI == 2) {
                if (q == 0) lbufw[row] = v[0] + extra;   // r==0 is the real logit col
            } else if constexpr (EPI == 3) {
                if (m < 2) *(f32x4*)(gpb + m*112 + col) = v;
            }
        }
    }
}

// ---------------------------------------------------------------------------
// Prep: build fp16 weight fragments (byte-identical to previous layout) plus
// zero-padded f32 bias tables. One 16x32 tile per block; t==0 writes bias.
// ---------------------------------------------------------------------------
struct PrepDesc { const float* w; half_t* out; const float* b; float* bout;
                  int K, C, KS, NT, CB, toff; };
struct PrepArgs { PrepDesc d[11]; };

__global__ __launch_bounds__(64) void k_prep(PrepArgs a) {
    const int blk = blockIdx.x, lane = threadIdx.x;
    int li = 0;
    #pragma unroll
    for (int i = 1; i < 11; ++i) if (blk >= a.d[i].toff) li = i;
    const PrepDesc d = a.d[li];
    const int t = blk - d.toff;
    const int ks = t / d.NT, nt = t - (t / d.NT) * d.NT;
    const int c = nt*16 + (lane & 15);
    half_t* o = d.out + ((size_t)(ks*d.NT + nt))*512 + lane*8;
    half8 hv;
    #pragma unroll
    for (int j = 0; j < 8; ++j) {
        const int k = ks*32 + (lane >> 4)*8 + j;
        float v = (k < d.K && c < d.C) ? d.w[(size_t)k*d.C + c] : 0.f;
        hv[j] = (half_t)v;
    }
    *(half8*)o = hv;
    if (t == 0 && d.CB > 0) {
        for (int u = lane; u < d.CB; u += 64)
            d.bout[u] = (u < d.C) ? d.b[u] : 0.f;
    }
}

// ---------------------------------------------------------------------------
// k_main: 256 threads = 4 independent waves, 2 elements each. Barrier-free.
// ---------------------------------------------------------------------------
__global__ __launch_bounds__(256, 2) void k_main(
    const float* __restrict__ state,
    const half_t* __restrict__ wfrag,
    const float* __restrict__ bL0, const float* __restrict__ bL1,
    const float* __restrict__ bL2, const float* __restrict__ bL3,
    const float* __restrict__ bL4, const float* __restrict__ bL6,
    const float* __restrict__ ab2,
    const float* __restrict__ bL8, const float* __restrict__ bL9,
    const float* __restrict__ bL10,
    const float* __restrict__ m3w3, const float* __restrict__ m3b3,
    float* __restrict__ out)
{
    __shared__ __align__(16) half_t S_all[4][48*SROW];
    __shared__ float gp_all[4][2*112];
    __shared__ float lb_all[4][48];

    const int tid = threadIdx.x;
    const int wv = tid >> 6, lane = tid & 63;
    const int m = lane & 15, q = lane >> 4;
    half_t* S = S_all[wv];
    float* gpb = gp_all[wv];
    float* lbufw = lb_all[wv];
    const int ebase = blockIdx.x * 8 + wv * 2;

    const half_t* wfL0 = wfrag;
    const half_t* wfL1 = wfL0 + 5120;
    const half_t* wfL2 = wfL1 + 17920;
    const half_t* wfL3 = wfL2 + 14336;
    const half_t* wfL4 = wfL3 + 8192;
    const half_t* wfL5 = wfL4 + 14336;
    const half_t* wfL6 = wfL5 + 14336;
    const half_t* wfL7 = wfL6 + 14336;
    const half_t* wfL8 = wfL7 + 2048;
    const half_t* wfL9 = wfL8 + 10240;
    const half_t* wfL10 = wfL9 + 17920;

    // ---- stage x: real rows 0..39 only, cols 0..31 (13 real + zero K-pad)
    {
        const float* xg = state + (size_t)ebase * 20 * 13;
        #pragma unroll
        for (int z = 0; z < 20; ++z) {
            const int u = z*64 + lane;
            const int r = u >> 5, c = u & 31;
            float v = (c < 13) ? xg[r*13 + c] : 0.f;
            S[r*SROW + c] = (half_t)v;
        }
    }

    // ---- L0: h1 = relu(x @ m1w0 + b) -> cols 0..160
    {
        half8 bf[1][3]; load_bf<1,3>(bf, S, m, q);
        run_layer<1,3,10,0,0,true>(bf, S, wfL0, bL0, gpb, lbufw, 0.f, lane);
    }
    // ---- L1: h = relu(h1 @ m1w1 + b) -> cols 0..112
    {
        half8 bf[5][3]; load_bf<5,3>(bf, S, m, q);
        run_layer<5,3,7,0,0,true>(bf, S, wfL1, bL1, gpb, lbufw, 0.f, lane);
    }
    // ---- keep h fragments in registers (serves L2 and L4)
    half8 hf[4][3]; load_bf<4,3>(hf, S, m, q);

    // ---- g = mean_n h -> strips at cols 112..168 rows {2e, 2e+1}; vectorized
    {
        const int ge = (lane >= 25) ? 1 : 0;
        const int gc = (lane - ge*25) * 4;          // col group base, 0..96
        if (lane < 50) {
            f32x4 s = {0.f,0.f,0.f,0.f};
            #pragma unroll
            for (int n = 0; n < 20; ++n) {
                half4 hv = *(const half4*)(S + (ge*20+n)*SROW + gc);
                s[0] += (float)hv[0]; s[1] += (float)hv[1];
                s[2] += (float)hv[2]; s[3] += (float)hv[3];
            }
            const int st = (gc >= 56) ? 1 : 0;
            half4 g4;
            g4[0] = (half_t)(s[0]*0.05f); g4[1] = (half_t)(s[1]*0.05f);
            g4[2] = (half_t)(s[2]*0.05f); g4[3] = (half_t)(s[3]*0.05f);
            *(half4*)(S + (2*ge+st)*SROW + 112 + (gc - st*56)) = g4;
        } else if (lane < 56) {
            // zero strip1 tail positions 44..55 (k-pad region gaf will read)
            const int u2 = lane - 50;               // 0..5
            const int le = (u2 >= 3) ? 1 : 0, lp = u2 - le*3;
            const half4 z4 = {};
            *(half4*)(S + (2*le+1)*SROW + 112 + 44 + lp*4) = z4;
        }
    }
    // ---- gp = g @ aw0[100:]  (B-frags of g; rows>=2 junk, store-guarded)
    {
        half8 gaf[4][1];
        #pragma unroll
        for (int ks = 0; ks < 4; ++ks) {
            const int c = q*8 + ks*32;
            const int s = (c >= 112) ? 2 : (c >= 56 ? 1 : 0);
            gaf[ks][0] = *(const half8*)(S + (2*m + s)*SROW + 112 + (c - s*56));
        }
        run_layer<4,1,7,3,0,false>(gaf, S, wfL5, nullptr, gpb, lbufw, 0.f, lane);
    }
    // ---- L2: fh = relu(h @ m2w0 + b)  (h from regs; cols 0..112 overwritten)
    run_layer<4,3,7,0,0,true>(hf, S, wfL2, bL2, gpb, lbufw, 0.f, lane);
    // ---- L3: f = fh @ m2w1 + b -> cols 112..168 (no relu)
    {
        half8 bf[4][3]; load_bf<4,3>(bf, S, m, q);
        run_layer<4,3,4,1,0,false>(bf, S, wfL3, bL3, gpb, lbufw, 0.f, lane);
    }
    // ---- L4: a1 = relu(h @ aw0[:100] + gp + ab0)
    run_layer<4,3,7,0,1,true>(hf, S, wfL4, bL4, gpb, lbufw, 0.f, lane);
    // ---- L6: a2 = relu(a1 @ aw1 + ab1)
    {
        half8 bf[4][3]; load_bf<4,3>(bf, S, m, q);
        run_layer<4,3,7,0,0,true>(bf, S, wfL6, bL6, gpb, lbufw, 0.f, lane);
    }
    // ---- L7: logits = a2 @ aw2 + ab2 -> lbufw
    {
        half8 bf[4][3]; load_bf<4,3>(bf, S, m, q);
        run_layer<4,3,1,2,0,false>(bf, S, wfL7, nullptr, gpb, lbufw, ab2[0], lane);
    }
    // ---- weighted + self -> joint tile (rows 0..15, cols 0..64) ----
    {
        f32x4 wacc = {0.f,0.f,0.f,0.f};
        const int we = (lane >= 13) ? 1 : 0;
        const int wj = (lane - we*13) * 4;          // 0..48
        if (lane < 26) {
            #pragma unroll
            for (int n = 0; n < 20; ++n) {
                half4 f4 = *(const half4*)(S + (we*20+n)*SROW + 112 + wj);
                const float a = lbufw[we*20 + n];
                wacc[0] += (float)f4[0] * a;
                wacc[1] += (float)f4[1] * a;
                wacc[2] += (float)f4[2] * a;
                wacc[3] += (float)f4[3] * a;
            }
        }
        float sv = 0.f;
        const int su = lane - 32;
        const int se = (su >= 6) ? 1 : 0, sd = su - se*6;
        if (lane >= 32 && lane < 44)
            sv = state[(size_t)(ebase + se)*260 + sd];
        // zero joint tile rows 0..15 cols 0..63 (b128)
        const half8 z8 = {};
        #pragma unroll
        for (int z = 0; z < 2; ++z) {
            const int u = z*64 + lane;
            *(half8*)(S + (u >> 3)*SROW + (u & 7)*8) = z8;
        }
        if (lane < 26) {
            half2v p0, p1;
            p0[0] = (half_t)wacc[0]; p0[1] = (half_t)wacc[1];
            p1[0] = (half_t)wacc[2]; p1[1] = (half_t)wacc[3];
            *(half2v*)(S + we*SROW + 6 + wj) = p0;
            *(half2v*)(S + we*SROW + 6 + wj + 2) = p1;
        }
        if (lane >= 32 && lane < 44)
            S[se*SROW + sd] = (half_t)sv;
    }
    // ---- head: v1 = relu(joint @ m3w0 + b0)  (rows 0..15, cols 0..160)
    {
        half8 bf[2][1]; load_bf<2,1>(bf, S, m, q);
        run_layer<2,1,10,0,0,true>(bf, S, wfL8, bL8, gpb, lbufw, 0.f, lane);
    }
    // ---- v2 = relu(v1 @ m3w1 + b1)
    {
        half8 bf[5][1]; load_bf<5,1>(bf, S, m, q);
        run_layer<5,1,7,0,0,true>(bf, S, wfL9, bL9, gpb, lbufw, 0.f, lane);
    }
    // ---- v3 = relu(v2 @ m3w2 + b2)
    {
        half8 bf[4][1]; load_bf<4,1>(bf, S, m, q);
        run_layer<4,1,7,0,0,true>(bf, S, wfL10, bL10, gpb, lbufw, 0.f, lane);
    }
    // ---- out[e] = v3[e] . m3w3 + b3   (lanes 0-31 -> elem 0, 32-63 -> elem 1)
    {
        const int e = lane >> 5, k = lane & 31;
        const half_t* vr = S + e*SROW;
        float s = (float)vr[k]      * m3w3[k]
                + (float)vr[k + 32] * m3w3[k + 32]
                + (float)vr[k + 64] * m3w3[k + 64];
        if (k < 4) s += (float)vr[k + 96] * m3w3[k + 96];
        #pragma unroll
        for (int off = 16; off > 0; off >>= 1)
            s += __shfl_down(s, off, 32);
        if (k == 0) out[ebase + e] = s + m3b3[0];
    }
}

extern "C" void kernel_launch(void* const* d_in, const int* in_sizes, int n_in,
                              void* d_out, int out_size, void* d_ws, size_t ws_size,
                              hipStream_t stream) {
    const float* state = (const float*)d_in[0];
    const float* m1w0 = (const float*)d_in[1];
    const float* m1b0 = (const float*)d_in[2];
    const float* m1w1 = (const float*)d_in[3];
    const float* m1b1 = (const float*)d_in[4];
    const float* m2w0 = (const float*)d_in[5];
    const float* m2b0 = (const float*)d_in[6];
    const float* m2w1 = (const float*)d_in[7];
    const float* m2b1 = (const float*)d_in[8];
    const float* aw0  = (const float*)d_in[9];
    const float* ab0  = (const float*)d_in[10];
    const float* aw1  = (const float*)d_in[11];
    const float* ab1  = (const float*)d_in[12];
    const float* aw2  = (const float*)d_in[13];
    const float* ab2  = (const float*)d_in[14];
    const float* m3w0 = (const float*)d_in[15];
    const float* m3b0 = (const float*)d_in[16];
    const float* m3w1 = (const float*)d_in[17];
    const float* m3b1 = (const float*)d_in[18];
    const float* m3w2 = (const float*)d_in[19];
    const float* m3b2 = (const float*)d_in[20];
    const float* m3w3 = (const float*)d_in[21];
    const float* m3b3 = (const float*)d_in[22];

    half_t* wfrag = (half_t*)d_ws;                 // 266,240 B of fragments
    float* biasws = (float*)(wfrag + 133120);      // 1056 padded bias floats

    PrepArgs pa;
    int off = 0; size_t hoff = 0; int idx = 0; int boff = 0;
    auto add = [&](const float* w, int K, int C, int KS, int NT,
                   const float* b, int CB) {
        pa.d[idx] = PrepDesc{w, wfrag + hoff, b, biasws + boff, K, C, KS, NT, CB, off};
        off += KS*NT;
        hoff += (size_t)KS*NT*512;
        boff += CB;
        ++idx;
    };
    add(m1w0, 13, 150, 1, 10, m1b0, 160);          // L0   bias @ 0
    add(m1w1, 150, 100, 5, 7, m1b1, 112);          // L1   bias @ 160
    add(m2w0, 100, 100, 4, 7, m2b0, 112);          // L2   bias @ 272
    add(m2w1, 100, 50, 4, 4, m2b1, 64);            // L3   bias @ 384
    add(aw0, 100, 100, 4, 7, ab0, 112);            // L4   bias @ 448
    add(aw0 + 100*100, 100, 100, 4, 7, nullptr, 0);// L5 (gp, no bias)
    add(aw1, 100, 100, 4, 7, ab1, 112);            // L6   bias @ 560
    add(aw2, 100, 1, 4, 1, nullptr, 0);            // L7 (ab2 handled as extra)
    add(m3w0, 56, 150, 2, 10, m3b0, 160);          // L8   bias @ 672
    add(m3w1, 150, 100, 5, 7, m3b1, 112);          // L9   bias @ 832
    add(m3w2, 100, 100, 4, 7, m3b2, 112);          // L10  bias @ 944

    k_prep<<<off, 64, 0, stream>>>(pa);

    const float* bb = biasws;
    k_main<<<NELEM/8, 256, 0, stream>>>(state, wfrag,
        bb + 0, bb + 160, bb + 272, bb + 384, bb + 448, bb + 560,
        ab2,
        bb + 672, bb + 832, bb + 944,
        m3w3, m3b3, (float*)d_out);
}